// Round 6
// baseline (210.979 us; speedup 1.0000x reference)
//
#include <hip/hip_runtime.h>
#include <math.h>

// DTW 2048x2048, squared-diff cost, out = sqrt(DTW[2047][2047]).
//
// NW=4 waves (256 thr) on one CU, R=8 rows/lane, lanes skewed 2 cols apart.
// Lane l of wave w owns rows 8*(64w+l)..+7, split into two INDEPENDENT
// 4-row chains: group A (rows 0-3) at col a = t-2l, group B (rows 4-7) at
// col b = a-1. ILP=2 fills dependent-VALU latency slots (round-5 lesson:
// the single 17-op chain ran at ~4cy/op; two 9-op chains interleave).
//
// Delivery (round-5 proven, nothing for the compiler to sink):
//  - per 64-step block: 2 coalesced ds_read_b32 (y[tau0+lane], ring[tau0+lane])
//  - per step: v_readlane(blk, s) (compile-time s) yields wave-uniform
//    scalars, injected into DPP wave_shr:1 conveyors:
//      u  : lane l-1's row-7 value (lane 0: ring injection)  [every step]
//      yP/yQ: dual y conveyor, shifted every 2 steps, 2 injections/shift;
//             yA = y[a], yB = y[b] = previous yA   [R4-validated wiring]
//  - B's up/diag: same-lane v3 (pre-update) / v3m1 (v3 one step back).
//
// Guard-free: INFV=1e30 absorbs adds; OOB cols (<0 ramp-in, >=2048 ramp-out)
// produce finite garbage confined to cols>=2048 / ring pads (DP flows
// right/down only, so garbage never reaches valid cells). One unified body
// for all blocks tau0 in [0,2112]; output stored at the unique step
// (w=3, lane=63, tau0=2112, s=62) where B's col == 2047.
//
// Ring rows unwrapped, PAD=128 (writes span cols -127..2174, reads ..2175).
// All lanes write row-7 each step; lane 63 writes each column last.
// DSKEW=192: producer writes col tau0+63 at its step tau0+190 — strictly
// before the consumer's block barrier (producer occupies [tau0+192,..) then).

#define NLEN  2048
#define NW    4
#define CSTEP 64
#define DSKEW 192
#define PAD   128
#define RROW  (PAD + 2176)     // 2304 floats per ring row
#define GTOT  2752             // last block: w=3, tau0=2112
#define TAUMAX 2112
#define INFV  1e30f

__device__ __forceinline__ float dpp_shr1(float v, float inj) {
    int r = __builtin_amdgcn_update_dpp(
        __builtin_bit_cast(int, inj), __builtin_bit_cast(int, v),
        0x138 /*wave_shr:1*/, 0xF, 0xF, false /*lane0 takes old=inj*/);
    return __builtin_bit_cast(float, r);
}
__device__ __forceinline__ float rdlane(float v, int l) {
    return __builtin_bit_cast(float,
        __builtin_amdgcn_readlane(__builtin_bit_cast(int, v), l));
}
__device__ __forceinline__ float min3f(float a, float b, float c) {
    return fminf(fminf(a, b), c);
}

__global__ __launch_bounds__(256, 1) void dtw_kernel(const float* __restrict__ X,
                                                     const float* __restrict__ Y,
                                                     float* __restrict__ out) {
    __shared__ __align__(16) float yS[NLEN];
    __shared__ float ring[(NW + 1) * RROW];

    const int tid  = threadIdx.x;
    const int w    = tid >> 6;
    const int lane = tid & 63;

    {
        const float4* Y4 = (const float4*)Y;
        float4* y4 = (float4*)yS;
        y4[tid]       = Y4[tid];
        y4[tid + 256] = Y4[tid + 256];
    }
    for (int k = tid; k < (NW + 1) * RROW; k += 256) ring[k] = INFV;
    __syncthreads();

    float x0, x1, x2, x3, x4, x5, x6, x7;
    {
        const float4 xa = *(const float4*)&X[tid * 8];
        const float4 xb = *(const float4*)&X[tid * 8 + 4];
        x0 = xa.x; x1 = xa.y; x2 = xa.z; x3 = xa.w;
        x4 = xb.x; x5 = xb.y; x6 = xb.z; x7 = xb.w;
    }

    float v0 = INFV, v1 = INFV, v2 = INFV, v3 = INFV;
    float v4 = INFV, v5 = INFV, v6 = INFV, v7 = INFV;
    float v3m1 = INFV;                        // v3 one step back (B's diag)
    float uprev = (tid == 0) ? 0.0f : INFV;   // DTW[-1][-1]=0 seed
    float yP = 0.0f, yQ = 0.0f, ym = 0.0f;    // y dual conveyor

    const float* ringR = ring + w * RROW + PAD;
    float*       ringW = ring + (w + 1) * RROW + PAD;

    for (int gb = 0; gb < GTOT; gb += CSTEP) {
        const int tau0 = gb - w * DSKEW;

        if (tau0 >= 0 && tau0 <= TAUMAX) {
            int yi = tau0 + lane;
            if (yi > NLEN - 1) yi = NLEN - 1;        // clamp (OOB cols only)
            const float yblk = yS[yi];               // coalesced ds_read
            const float rblk = ringR[tau0 + lane];   // coalesced ds_read
            float* wp = ringW + (tau0 - 2 * lane - 1);
            const bool isout = (tau0 == TAUMAX) & (w == NW - 1) & (lane == 63);

            #pragma unroll
            for (int s = 0; s < CSTEP; ++s) {
                const float ru = rdlane(rblk, s);    // ring[tau0+s]
                if ((s & 1) == 0) {
                    ym = yQ;
                    yP = dpp_shr1(yP, rdlane(yblk, s));
                    yQ = dpp_shr1(yQ, rdlane(yblk, s + 1));
                }
                const float yA = ((s & 1) == 0) ? yP : yQ;  // y[a]
                const float yB = ((s & 1) == 0) ? ym : yP;  // y[a-1]
                const float u  = dpp_shr1(v7, ru);          // lane l-1 row 7
                // group B: rows 4-7 at col a-1 (pre-update v3, v3m1)
                float d4 = x4 - yB; float nv4 = fmaf(d4, d4, min3f(v4, v3m1, v3));
                float d5 = x5 - yB; float nv5 = fmaf(d5, d5, min3f(v5, v4, nv4));
                float d6 = x6 - yB; float nv6 = fmaf(d6, d6, min3f(v6, v5, nv5));
                float d7 = x7 - yB; float nv7 = fmaf(d7, d7, min3f(v7, v6, nv6));
                // group A: rows 0-3 at col a
                float d0 = x0 - yA; float nv0 = fmaf(d0, d0, min3f(v0, uprev, u));
                float d1 = x1 - yA; float nv1 = fmaf(d1, d1, min3f(v1, v0, nv0));
                float d2 = x2 - yA; float nv2 = fmaf(d2, d2, min3f(v2, v1, nv1));
                float d3 = x3 - yA; float nv3 = fmaf(d3, d3, min3f(v3, v2, nv2));
                wp[s] = nv7;
                if (s == 62 && isout) out[0] = sqrtf(nv7);  // col 2047
                v3m1 = v3;
                v0 = nv0; v1 = nv1; v2 = nv2; v3 = nv3;
                v4 = nv4; v5 = nv5; v6 = nv6; v7 = nv7;
                uprev = u;
            }
        }
        __syncthreads();
    }
}

extern "C" void kernel_launch(void* const* d_in, const int* in_sizes, int n_in,
                              void* d_out, int out_size, void* d_ws, size_t ws_size,
                              hipStream_t stream) {
    const float* x = (const float*)d_in[0];
    const float* y = (const float*)d_in[1];
    (void)in_sizes; (void)n_in; (void)out_size; (void)d_ws; (void)ws_size;
    dtw_kernel<<<1, 256, 0, stream>>>(x, y, (float*)d_out);
}